// Round 7
// baseline (767.529 us; speedup 1.0000x reference)
//
#include <hip/hip_runtime.h>
#include <hip/hip_bf16.h>
#include <cstddef>
#include <cstdint>

typedef _Float16 f16;
typedef unsigned int u32;

#define Mtok  16384
#define Ncode 8192
#define Kdim  256
#define NSPLIT 8
#define NPER  (Ncode / NSPLIT)    // 1024 codes per split

typedef f16   f16x8 __attribute__((ext_vector_type(8)));
typedef f16   f16x4 __attribute__((ext_vector_type(4)));
typedef float f32x4 __attribute__((ext_vector_type(4)));

#define LDSP(p) ((__attribute__((address_space(3))) void*)(p))
#define GPTR(p) ((const __attribute__((address_space(1))) void*)(p))

// ---------------------------------------------------------------------------
// Kernel 1: transpose z -> z_out (fp32) + sh = fp16(-2z) [Mtok][256].
// Also zeroes the rescue counter (stream-ordered before k_merge).
__global__ __launch_bounds__(256) void k_prep(const float* __restrict__ z,
        float* __restrict__ z_out, f16* __restrict__ sh, int* __restrict__ count) {
    __shared__ float tile[32][33];
    const int b  = blockIdx.z;
    const int c0 = blockIdx.y * 32;
    const int p0 = blockIdx.x * 32;
    const int tx = threadIdx.x;   // 0..31
    const int ty = threadIdx.y;   // 0..7
    if (b == 0 && c0 == 0 && p0 == 0 && tx == 0 && ty == 0) count[0] = 0;
    const float* src = z + ((size_t)b * Kdim + c0) * 1024 + p0;
#pragma unroll
    for (int i = 0; i < 32; i += 8)
        tile[ty + i][tx] = src[(size_t)(ty + i) * 1024 + tx];
    __syncthreads();
#pragma unroll
    for (int i = 0; i < 32; i += 8) {
        const float v = tile[tx][ty + i];
        const size_t m = (size_t)b * 1024 + p0 + ty + i;
        const int    c = c0 + tx;
        z_out[m * Kdim + c] = v;
        sh[m * Kdim + c] = (f16)(-2.0f * v);
    }
}

// ---------------------------------------------------------------------------
// Kernel 2: wnorm[n]=||w_n||^2, whc = fp16(w) in chunk-major layout
// [c=k/8][n][8] (16B pieces), and wmax = max float-bits of wnorm via signed
// atomicMax (0xAA poison is negative -> no init needed). One wave per row.
__global__ __launch_bounds__(64) void k_wsplit(const float* __restrict__ w,
        float* __restrict__ wnorm, f16* __restrict__ whc, int* __restrict__ wmax) {
    const int row  = blockIdx.x;
    const int lane = threadIdx.x;
    const float4 v = ((const float4*)(w + (size_t)row * Kdim))[lane];
    float s = v.x * v.x + v.y * v.y + v.z * v.z + v.w * v.w;
#pragma unroll
    for (int off = 32; off > 0; off >>= 1)
        s += __shfl_down(s, off, 64);
    if (lane == 0) {
        wnorm[row] = s;
        atomicMax(wmax, __float_as_int(s));   // s > 0 -> bits ordered as int
    }
    const int c   = lane >> 1;          // chunk 0..31
    const int pos = (lane & 1) * 4;
    f16x4 p;
    p[0] = (f16)v.x; p[1] = (f16)v.y; p[2] = (f16)v.z; p[3] = (f16)v.w;
    *(f16x4*)(whc + ((size_t)c * Ncode + row) * 8 + pos) = p;
}

// ---------------------------------------------------------------------------
// Kernel 3: fp16 single-pass MFMA distance GEMM + packed top-2.
// d~(m,n) = wnorm[n] + 1024 + sum sh*wh  (fp32 acc; +1024 keeps f positive
// so uint compare == float compare). key = (bits(f) & ~63) | (nt*2+j).
__global__ __launch_bounds__(256, 2) void k_mfma(
        const f16* __restrict__ sh, const f16* __restrict__ whc,
        const float* __restrict__ wnorm,
        float* __restrict__ pv1, int* __restrict__ pi1, float* __restrict__ pv2) {
    __shared__ __align__(16) f16 Bs[32 * 256];   // [chunk][32 rows][8] = 16 KB
    const int tid  = threadIdx.x;
    const int w    = tid >> 6;          // wave 0..3
    const int lane = tid & 63;
    const int l15  = lane & 15;
    const int q    = lane >> 4;         // 0..3
    const int y    = blockIdx.x & 7;    // n-split
    const int x    = blockIdx.x >> 3;   // m-tile 0..63
    const int m0   = x * 256;
    const int n0   = y * NPER;

    f16x8 a[4][8];
#pragma unroll
    for (int i = 0; i < 4; ++i)
#pragma unroll
        for (int c = 0; c < 8; ++c)
            a[i][c] = *(const f16x8*)(sh +
                (size_t)(m0 + w * 64 + i * 16 + l15) * Kdim + c * 32 + q * 8);

    u32 u1[16], u2[16];
#pragma unroll
    for (int s = 0; s < 16; ++s) { u1[s] = 0xFFFFFFFFu; u2[s] = 0xFFFFFFFFu; }

#pragma unroll 1
    for (int nt = 0; nt < NPER / 32; ++nt) {   // 32 code-tiles of 32
        const int nb = n0 + nt * 32;
        __syncthreads();
#pragma unroll
        for (int ii = 0; ii < 4; ++ii) {
            const int c2 = (w * 4 + ii) * 2;
            const int ch = c2 + (lane >> 5);
            const int nr = lane & 31;
            __builtin_amdgcn_global_load_lds(
                GPTR(whc + ((size_t)ch * Ncode + nb + nr) * 8),
                LDSP(Bs + (size_t)c2 * 256), 16, 0, 0);
        }
        __syncthreads();
        f32x4 acc[4][2];
#pragma unroll
        for (int j = 0; j < 2; ++j) {
            const float wv = wnorm[nb + j * 16 + l15] + 1024.0f;
#pragma unroll
            for (int i = 0; i < 4; ++i) {
                acc[i][j][0] = wv; acc[i][j][1] = wv;
                acc[i][j][2] = wv; acc[i][j][3] = wv;
            }
        }
#pragma unroll
        for (int cc = 0; cc < 8; ++cc)
#pragma unroll
            for (int j = 0; j < 2; ++j) {
                const f16x8 b = *(const f16x8*)&Bs[(cc * 4 + q) * 256 + (j * 16 + l15) * 8];
#pragma unroll
                for (int i = 0; i < 4; ++i)
                    acc[i][j] = __builtin_amdgcn_mfma_f32_16x16x32_f16(
                        a[i][cc], b, acc[i][j], 0, 0, 0);
            }
#pragma unroll
        for (int i = 0; i < 4; ++i)
#pragma unroll
            for (int j = 0; j < 2; ++j)
#pragma unroll
                for (int r = 0; r < 4; ++r) {
                    const int s = i * 4 + r;
                    const u32 key = (__float_as_uint(acc[i][j][r]) & 0xFFFFFFC0u)
                                    | (u32)(nt * 2 + j);
                    const u32 t2 = u1[s] > key ? u1[s] : key;   // max
                    u2[s] = u2[s] < t2 ? u2[s] : t2;            // min -> 2nd
                    u1[s] = u1[s] < key ? u1[s] : key;          // min
                }
    }
    float v1[16], v2[16]; int i1[16];
#pragma unroll
    for (int s = 0; s < 16; ++s) {
        v1[s] = __uint_as_float(u1[s] & 0xFFFFFFC0u);
        v2[s] = __uint_as_float(u2[s] & 0xFFFFFFC0u);
        const int local = (int)(u1[s] & 63u);
        i1[s] = n0 + (local >> 1) * 32 + (local & 1) * 16 + l15;
    }
#pragma unroll
    for (int msk = 1; msk < 16; msk <<= 1) {
#pragma unroll
        for (int s = 0; s < 16; ++s) {
            const float ov1 = __shfl_xor(v1[s], msk, 64);
            const int   oi1 = __shfl_xor(i1[s], msk, 64);
            const float ov2 = __shfl_xor(v2[s], msk, 64);
            const bool  keep = (v1[s] < ov1) || (v1[s] == ov1 && i1[s] < oi1);
            const float lose = keep ? ov1 : v1[s];
            v1[s] = keep ? v1[s] : ov1;
            i1[s] = keep ? i1[s] : oi1;
            v2[s] = fminf(fminf(v2[s], ov2), lose);
        }
    }
    if (l15 == 0) {
#pragma unroll
        for (int i = 0; i < 4; ++i)
#pragma unroll
            for (int r = 0; r < 4; ++r) {
                const int s = i * 4 + r;
                const int m = m0 + w * 64 + i * 16 + q * 4 + r;
                pv1[(size_t)y * Mtok + m] = v1[s];
                pi1[(size_t)y * Mtok + m] = i1[s];
                pv2[(size_t)y * Mtok + m] = v2[s];
            }
    }
}

// ---------------------------------------------------------------------------
// Kernel 4: per-token merge of 8 split partials + rigorous flag threshold.
__global__ __launch_bounds__(256) void k_merge(
        const f16* __restrict__ sh,
        const float* __restrict__ pv1, const int* __restrict__ pi1,
        const float* __restrict__ pv2, const int* __restrict__ wmax,
        int* __restrict__ fidx, int* __restrict__ flag,
        int* __restrict__ list, int* __restrict__ count) {
    const int t    = blockIdx.x * 4 + (threadIdx.x >> 6);
    const int lane = threadIdx.x & 63;
    const f16x4 p = *(const f16x4*)(sh + (size_t)t * Kdim + lane * 4);
    float s2 = 0.f;
#pragma unroll
    for (int i = 0; i < 4; ++i) { const float e = (float)p[i]; s2 = fmaf(e, e, s2); }
#pragma unroll
    for (int off = 32; off > 0; off >>= 1)
        s2 += __shfl_down(s2, off, 64);
    if (lane == 0) {
        float b1 = 3.0e38f, b2 = 3.0e38f; int bi = 0x7fffffff;
#pragma unroll
        for (int s = 0; s < NSPLIT; ++s) {
            const float v1 = pv1[(size_t)s * Mtok + t];
            const int   i1 = pi1[(size_t)s * Mtok + t];
            const float v2 = pv2[(size_t)s * Mtok + t];
            const bool  wn = (v1 < b1) || (v1 == b1 && i1 < bi);
            const float lose = wn ? b1 : v1;
            b2 = fminf(fminf(b2, v2), lose);
            b1 = wn ? v1 : b1;
            bi = wn ? i1 : bi;
        }
        fidx[t] = bi;
        const float Wm = sqrtf(__int_as_float(wmax[0]));
        const float th = 0.00205f * sqrtf(s2) * Wm + 0.12f;
        const int f = (b2 - b1 < th) ? 1 : 0;
        flag[t] = f;
        if (f) { const int pos = atomicAdd(count, 1); list[pos] = t; }
    }
}

// ---------------------------------------------------------------------------
// Kernel 5: exact fp32 rescue as a tiled coalesced GEMM-argmin over the
// compacted flagged list. Grid (256 tiles x 8 splits), uniform early exit
// past count. Tile: 64 tokens (gathered) x 128 codes, TK=32, k-major LDS.
// Per thread: 4 tokens x 8 codes. Same exact-fp32 + lex-first-min semantics
// as the reference argmin. Partial top-1 per (token, split) -> pcv/pci.
__global__ __launch_bounds__(256) void k_rescue(
        const float* __restrict__ zt, const float* __restrict__ w,
        const float* __restrict__ wnorm, const int* __restrict__ list,
        const int* __restrict__ count,
        float* __restrict__ pcv, int* __restrict__ pci) {
    const int cnt = count[0];
    const int m0  = blockIdx.x * 64;
    if (m0 >= cnt) return;
    __shared__ float Zs[32][68];      // [k][m], k-major, +4 pad
    __shared__ float Ws[32][132];     // [k][deinterleaved n], +4 pad
    __shared__ int   rowid[64];
    const int tid = threadIdx.x;
    const int cg  = tid & 15;         // 8 codes
    const int rg  = tid >> 4;         // 4 tokens
    const int y   = blockIdx.y;
    const int n0  = y * NPER;
    if (tid < 64) rowid[tid] = list[min(m0 + tid, cnt - 1)];
    __syncthreads();

    float minv[4]; int mini[4];
#pragma unroll
    for (int i = 0; i < 4; ++i) { minv[i] = 3.0e38f; mini[i] = 0x7fffffff; }

#pragma unroll 1
    for (int nt = 0; nt < NPER / 128; ++nt) {
        const int nb = n0 + nt * 128;
        float acc[4][8];
#pragma unroll
        for (int j = 0; j < 8; ++j) {
            const float wn = wnorm[nb + cg * 8 + j];
#pragma unroll
            for (int i = 0; i < 4; ++i) acc[i][j] = wn;
        }
#pragma unroll 1
        for (int k0 = 0; k0 < Kdim; k0 += 32) {
            __syncthreads();
#pragma unroll
            for (int p = 0; p < 2; ++p) {            // Z: 64 rows x 8 slots
                const int qq = p * 256 + tid;
                const int r  = qq >> 3, f = qq & 7;
                const float4 v = *(const float4*)(zt + (size_t)rowid[r] * Kdim + k0 + f * 4);
                Zs[f * 4 + 0][r] = -2.0f * v.x;
                Zs[f * 4 + 1][r] = -2.0f * v.y;
                Zs[f * 4 + 2][r] = -2.0f * v.z;
                Zs[f * 4 + 3][r] = -2.0f * v.w;
            }
#pragma unroll
            for (int p = 0; p < 4; ++p) {            // W: 128 rows x 8 slots
                const int qq = p * 256 + tid;
                const int r  = qq >> 3, f = qq & 7;
                const float4 u = *(const float4*)(w + (size_t)(nb + r) * Kdim + k0 + f * 4);
                const int pos = ((r & 4) ? 64 : 0) + (r >> 3) * 4 + (r & 3);
                Ws[f * 4 + 0][pos] = u.x;
                Ws[f * 4 + 1][pos] = u.y;
                Ws[f * 4 + 2][pos] = u.z;
                Ws[f * 4 + 3][pos] = u.w;
            }
            __syncthreads();
#pragma unroll 4
            for (int k = 0; k < 32; ++k) {
                const float4 za  = *(const float4*)&Zs[k][rg * 4];
                const float4 wb0 = *(const float4*)&Ws[k][cg * 4];
                const float4 wb1 = *(const float4*)&Ws[k][64 + cg * 4];
                const float zr[4] = {za.x, za.y, za.z, za.w};
                const float wb[8] = {wb0.x, wb0.y, wb0.z, wb0.w,
                                     wb1.x, wb1.y, wb1.z, wb1.w};
#pragma unroll
                for (int i = 0; i < 4; ++i)
#pragma unroll
                    for (int j = 0; j < 8; ++j)
                        acc[i][j] = fmaf(zr[i], wb[j], acc[i][j]);
            }
        }
#pragma unroll
        for (int i = 0; i < 4; ++i)
#pragma unroll
            for (int j = 0; j < 8; ++j) {
                const float v  = acc[i][j];
                const int idx  = nb + cg * 8 + j;
                if (v < minv[i] || (v == minv[i] && idx < mini[i])) {
                    minv[i] = v; mini[i] = idx;
                }
            }
    }
    // cross-cg reduction: 16 partials per token row
    __syncthreads();
    float* redv = (float*)&Zs[0][0];   // [64][16]
    int*   redi = (int*)&Ws[0][0];
#pragma unroll
    for (int i = 0; i < 4; ++i) {
        redv[(rg * 4 + i) * 16 + cg] = minv[i];
        redi[(rg * 4 + i) * 16 + cg] = mini[i];
    }
    __syncthreads();
    if (tid < 64) {
        float bv = 3.0e38f; int bi = 0x7fffffff;
#pragma unroll
        for (int c = 0; c < 16; ++c) {
            const float v = redv[tid * 16 + c];
            const int   x = redi[tid * 16 + c];
            if (v < bv || (v == bv && x < bi)) { bv = v; bi = x; }
        }
        pcv[(size_t)rowid[tid] * NSPLIT + y] = bv;
        pci[(size_t)rowid[tid] * NSPLIT + y] = bi;
    }
}

// ---------------------------------------------------------------------------
// Kernel 6: gather z_q = weight[idx] + float indices; flagged tokens merge
// their 8 exact rescue partials in-wave first (inf-padded butterfly).
__global__ __launch_bounds__(256) void k_gather(
        const float* __restrict__ w, const int* __restrict__ fidx,
        const int* __restrict__ flag,
        const float* __restrict__ pcv, const int* __restrict__ pci,
        float* __restrict__ zq, float* __restrict__ idx_out) {
    const int token = blockIdx.x * 4 + (threadIdx.x >> 6);
    const int lane  = threadIdx.x & 63;
    int bi = fidx[token];
    if (flag[token]) {
        float v = 3.0e38f; int ii = 0x7fffffff;
        if (lane < NSPLIT) {
            v  = pcv[(size_t)token * NSPLIT + lane];
            ii = pci[(size_t)token * NSPLIT + lane];
        }
#pragma unroll
        for (int msk = 1; msk < 64; msk <<= 1) {
            const float ov = __shfl_xor(v, msk, 64);
            const int   oi = __shfl_xor(ii, msk, 64);
            if (ov < v || (ov == v && oi < ii)) { v = ov; ii = oi; }
        }
        bi = ii;
    }
    const float4 u = *(const float4*)(w + (size_t)bi * Kdim + lane * 4);
    *(float4*)(zq + (size_t)token * Kdim + lane * 4) = u;
    if (lane == 0) idx_out[token] = (float)bi;
}

// ---------------------------------------------------------------------------
extern "C" void kernel_launch(void* const* d_in, const int* in_sizes, int n_in,
                              void* d_out, int out_size, void* d_ws, size_t ws_size,
                              hipStream_t stream) {
    const float* z = (const float*)d_in[0];
    const float* w = (const float*)d_in[1];

    float* z_out  = (float*)d_out;                          // [16384, 256]
    float* zq     = z_out + (size_t)Mtok * Kdim;            // [16384, 256]
    float* idxout = zq + (size_t)Mtok * Kdim;               // [16384]

    char* ws = (char*)d_ws;
    f16*   sh    = (f16*)ws;                       ws += (size_t)Mtok * Kdim * 2;
    f16*   whc   = (f16*)ws;                       ws += (size_t)Ncode * Kdim * 2;
    float* wnorm = (float*)ws;                     ws += (size_t)Ncode * 4;
    float* pv1   = (float*)ws;                     ws += (size_t)NSPLIT * Mtok * 4;
    int*   pi1   = (int*)ws;                       ws += (size_t)NSPLIT * Mtok * 4;
    float* pv2   = (float*)ws;                     ws += (size_t)NSPLIT * Mtok * 4;
    int*   fidx  = (int*)ws;                       ws += (size_t)Mtok * 4;
    int*   flag  = (int*)ws;                       ws += (size_t)Mtok * 4;
    int*   list  = (int*)ws;                       ws += (size_t)Mtok * 4;
    int*   count = (int*)ws;                       ws += 128;
    int*   wmax  = (int*)ws;                       ws += 128;
    float* pcv   = (float*)ws;                     ws += (size_t)Mtok * NSPLIT * 4;
    int*   pci   = (int*)ws;                       ws += (size_t)Mtok * NSPLIT * 4;

    k_prep<<<dim3(1024 / 32, Kdim / 32, 16), dim3(32, 8), 0, stream>>>(z, z_out, sh, count);
    k_wsplit<<<dim3(Ncode), dim3(64), 0, stream>>>(w, wnorm, whc, wmax);
    k_mfma<<<dim3((Mtok / 256) * NSPLIT), dim3(256), 0, stream>>>(sh, whc, wnorm,
                                                                  pv1, pi1, pv2);
    k_merge<<<dim3(Mtok / 4), dim3(256), 0, stream>>>(sh, pv1, pi1, pv2, wmax,
                                                      fidx, flag, list, count);
    k_rescue<<<dim3(Mtok / 64, NSPLIT), dim3(256), 0, stream>>>(z_out, w, wnorm,
                                                                list, count, pcv, pci);
    k_gather<<<dim3(Mtok / 4), dim3(256), 0, stream>>>(w, fidx, flag, pcv, pci,
                                                       zq, idxout);
}

// Round 8
// 493.740 us; speedup vs baseline: 1.5545x; 1.5545x over previous
//
#include <hip/hip_runtime.h>
#include <hip/hip_bf16.h>
#include <cstddef>
#include <cstdint>

typedef _Float16 f16;
typedef unsigned int u32;

#define Mtok  16384
#define Ncode 8192
#define Kdim  256
#define NSPLIT 8
#define NPER  (Ncode / NSPLIT)    // 1024 codes per split (MFMA kernel)
#define RSPLIT 32                 // rescue splits (finer grain for occupancy)
#define RPER  (Ncode / RSPLIT)    // 256 codes per rescue split

typedef f16   f16x8 __attribute__((ext_vector_type(8)));
typedef f16   f16x4 __attribute__((ext_vector_type(4)));
typedef float f32x4 __attribute__((ext_vector_type(4)));

#define LDSP(p) ((__attribute__((address_space(3))) void*)(p))
#define GPTR(p) ((const __attribute__((address_space(1))) void*)(p))

// ---------------------------------------------------------------------------
// Kernel 1: transpose z -> z_out (fp32) + sh = fp16(-2z) [Mtok][256].
// Also zeroes the rescue counter (stream-ordered before k_merge).
__global__ __launch_bounds__(256) void k_prep(const float* __restrict__ z,
        float* __restrict__ z_out, f16* __restrict__ sh, int* __restrict__ count) {
    __shared__ float tile[32][33];
    const int b  = blockIdx.z;
    const int c0 = blockIdx.y * 32;
    const int p0 = blockIdx.x * 32;
    const int tx = threadIdx.x;   // 0..31
    const int ty = threadIdx.y;   // 0..7
    if (b == 0 && c0 == 0 && p0 == 0 && tx == 0 && ty == 0) count[0] = 0;
    const float* src = z + ((size_t)b * Kdim + c0) * 1024 + p0;
#pragma unroll
    for (int i = 0; i < 32; i += 8)
        tile[ty + i][tx] = src[(size_t)(ty + i) * 1024 + tx];
    __syncthreads();
#pragma unroll
    for (int i = 0; i < 32; i += 8) {
        const float v = tile[tx][ty + i];
        const size_t m = (size_t)b * 1024 + p0 + ty + i;
        const int    c = c0 + tx;
        z_out[m * Kdim + c] = v;
        sh[m * Kdim + c] = (f16)(-2.0f * v);
    }
}

// ---------------------------------------------------------------------------
// Kernel 2: wnorm[n]=||w_n||^2, whc = fp16(w) in chunk-major layout
// [c=k/8][n][8] (16B pieces), and wmax = max float-bits of wnorm via signed
// atomicMax (0xAA poison is negative -> no init needed). One wave per row.
__global__ __launch_bounds__(64) void k_wsplit(const float* __restrict__ w,
        float* __restrict__ wnorm, f16* __restrict__ whc, int* __restrict__ wmax) {
    const int row  = blockIdx.x;
    const int lane = threadIdx.x;
    const float4 v = ((const float4*)(w + (size_t)row * Kdim))[lane];
    float s = v.x * v.x + v.y * v.y + v.z * v.z + v.w * v.w;
#pragma unroll
    for (int off = 32; off > 0; off >>= 1)
        s += __shfl_down(s, off, 64);
    if (lane == 0) {
        wnorm[row] = s;
        atomicMax(wmax, __float_as_int(s));   // s > 0 -> bits ordered as int
    }
    const int c   = lane >> 1;          // chunk 0..31
    const int pos = (lane & 1) * 4;
    f16x4 p;
    p[0] = (f16)v.x; p[1] = (f16)v.y; p[2] = (f16)v.z; p[3] = (f16)v.w;
    *(f16x4*)(whc + ((size_t)c * Ncode + row) * 8 + pos) = p;
}

// ---------------------------------------------------------------------------
// Kernel 3: fp16 single-pass MFMA distance GEMM + packed top-2.
// d~(m,n) = wnorm[n] + 1024 + sum sh*wh  (fp32 acc; +1024 keeps f positive
// so uint compare == float compare). key = (bits(f) & ~63) | (nt*2+j).
__global__ __launch_bounds__(256, 2) void k_mfma(
        const f16* __restrict__ sh, const f16* __restrict__ whc,
        const float* __restrict__ wnorm,
        float* __restrict__ pv1, int* __restrict__ pi1, float* __restrict__ pv2) {
    __shared__ __align__(16) f16 Bs[32 * 256];   // [chunk][32 rows][8] = 16 KB
    const int tid  = threadIdx.x;
    const int w    = tid >> 6;          // wave 0..3
    const int lane = tid & 63;
    const int l15  = lane & 15;
    const int q    = lane >> 4;         // 0..3
    const int y    = blockIdx.x & 7;    // n-split
    const int x    = blockIdx.x >> 3;   // m-tile 0..63
    const int m0   = x * 256;
    const int n0   = y * NPER;

    f16x8 a[4][8];
#pragma unroll
    for (int i = 0; i < 4; ++i)
#pragma unroll
        for (int c = 0; c < 8; ++c)
            a[i][c] = *(const f16x8*)(sh +
                (size_t)(m0 + w * 64 + i * 16 + l15) * Kdim + c * 32 + q * 8);

    u32 u1[16], u2[16];
#pragma unroll
    for (int s = 0; s < 16; ++s) { u1[s] = 0xFFFFFFFFu; u2[s] = 0xFFFFFFFFu; }

#pragma unroll 1
    for (int nt = 0; nt < NPER / 32; ++nt) {   // 32 code-tiles of 32
        const int nb = n0 + nt * 32;
        __syncthreads();
#pragma unroll
        for (int ii = 0; ii < 4; ++ii) {
            const int c2 = (w * 4 + ii) * 2;
            const int ch = c2 + (lane >> 5);
            const int nr = lane & 31;
            __builtin_amdgcn_global_load_lds(
                GPTR(whc + ((size_t)ch * Ncode + nb + nr) * 8),
                LDSP(Bs + (size_t)c2 * 256), 16, 0, 0);
        }
        __syncthreads();
        f32x4 acc[4][2];
#pragma unroll
        for (int j = 0; j < 2; ++j) {
            const float wv = wnorm[nb + j * 16 + l15] + 1024.0f;
#pragma unroll
            for (int i = 0; i < 4; ++i) {
                acc[i][j][0] = wv; acc[i][j][1] = wv;
                acc[i][j][2] = wv; acc[i][j][3] = wv;
            }
        }
#pragma unroll
        for (int cc = 0; cc < 8; ++cc)
#pragma unroll
            for (int j = 0; j < 2; ++j) {
                const f16x8 b = *(const f16x8*)&Bs[(cc * 4 + q) * 256 + (j * 16 + l15) * 8];
#pragma unroll
                for (int i = 0; i < 4; ++i)
                    acc[i][j] = __builtin_amdgcn_mfma_f32_16x16x32_f16(
                        a[i][cc], b, acc[i][j], 0, 0, 0);
            }
#pragma unroll
        for (int i = 0; i < 4; ++i)
#pragma unroll
            for (int j = 0; j < 2; ++j)
#pragma unroll
                for (int r = 0; r < 4; ++r) {
                    const int s = i * 4 + r;
                    const u32 key = (__float_as_uint(acc[i][j][r]) & 0xFFFFFFC0u)
                                    | (u32)(nt * 2 + j);
                    const u32 t2 = u1[s] > key ? u1[s] : key;   // max
                    u2[s] = u2[s] < t2 ? u2[s] : t2;            // min -> 2nd
                    u1[s] = u1[s] < key ? u1[s] : key;          // min
                }
    }
    float v1[16], v2[16]; int i1[16];
#pragma unroll
    for (int s = 0; s < 16; ++s) {
        v1[s] = __uint_as_float(u1[s] & 0xFFFFFFC0u);
        v2[s] = __uint_as_float(u2[s] & 0xFFFFFFC0u);
        const int local = (int)(u1[s] & 63u);
        i1[s] = n0 + (local >> 1) * 32 + (local & 1) * 16 + l15;
    }
#pragma unroll
    for (int msk = 1; msk < 16; msk <<= 1) {
#pragma unroll
        for (int s = 0; s < 16; ++s) {
            const float ov1 = __shfl_xor(v1[s], msk, 64);
            const int   oi1 = __shfl_xor(i1[s], msk, 64);
            const float ov2 = __shfl_xor(v2[s], msk, 64);
            const bool  keep = (v1[s] < ov1) || (v1[s] == ov1 && i1[s] < oi1);
            const float lose = keep ? ov1 : v1[s];
            v1[s] = keep ? v1[s] : ov1;
            i1[s] = keep ? i1[s] : oi1;
            v2[s] = fminf(fminf(v2[s], ov2), lose);
        }
    }
    if (l15 == 0) {
#pragma unroll
        for (int i = 0; i < 4; ++i)
#pragma unroll
            for (int r = 0; r < 4; ++r) {
                const int s = i * 4 + r;
                const int m = m0 + w * 64 + i * 16 + q * 4 + r;
                pv1[(size_t)y * Mtok + m] = v1[s];
                pi1[(size_t)y * Mtok + m] = i1[s];
                pv2[(size_t)y * Mtok + m] = v2[s];
            }
    }
}

// ---------------------------------------------------------------------------
// Kernel 4: per-token merge of 8 split partials + rigorous flag threshold.
__global__ __launch_bounds__(256) void k_merge(
        const f16* __restrict__ sh,
        const float* __restrict__ pv1, const int* __restrict__ pi1,
        const float* __restrict__ pv2, const int* __restrict__ wmax,
        int* __restrict__ fidx, int* __restrict__ flag,
        int* __restrict__ list, int* __restrict__ count) {
    const int t    = blockIdx.x * 4 + (threadIdx.x >> 6);
    const int lane = threadIdx.x & 63;
    const f16x4 p = *(const f16x4*)(sh + (size_t)t * Kdim + lane * 4);
    float s2 = 0.f;
#pragma unroll
    for (int i = 0; i < 4; ++i) { const float e = (float)p[i]; s2 = fmaf(e, e, s2); }
#pragma unroll
    for (int off = 32; off > 0; off >>= 1)
        s2 += __shfl_down(s2, off, 64);
    if (lane == 0) {
        float b1 = 3.0e38f, b2 = 3.0e38f; int bi = 0x7fffffff;
#pragma unroll
        for (int s = 0; s < NSPLIT; ++s) {
            const float v1 = pv1[(size_t)s * Mtok + t];
            const int   i1 = pi1[(size_t)s * Mtok + t];
            const float v2 = pv2[(size_t)s * Mtok + t];
            const bool  wn = (v1 < b1) || (v1 == b1 && i1 < bi);
            const float lose = wn ? b1 : v1;
            b2 = fminf(fminf(b2, v2), lose);
            b1 = wn ? v1 : b1;
            bi = wn ? i1 : bi;
        }
        fidx[t] = bi;
        const float Wm = sqrtf(__int_as_float(wmax[0]));
        const float th = 0.00205f * sqrtf(s2) * Wm + 0.12f;
        const int f = (b2 - b1 < th) ? 1 : 0;
        flag[t] = f;
        if (f) { const int pos = atomicAdd(count, 1); list[pos] = t; }
    }
}

// ---------------------------------------------------------------------------
// Kernel 5: exact fp32 rescue, tiled GEMM-argmin over the compacted flagged
// list. RSPLIT=32 fine-grained code splits (256 codes each) so that at
// cnt~1.5K the active-block count is ~768 (3/CU) instead of 192 (round-7
// occupancy failure: 9.8% occ, 16% VALUBusy). Tile: 64 tokens x 128 codes,
// 2 nt-iterations. Exact fp32 + lex-first-min semantics.
__global__ __launch_bounds__(256) void k_rescue(
        const float* __restrict__ zt, const float* __restrict__ w,
        const float* __restrict__ wnorm, const int* __restrict__ list,
        const int* __restrict__ count,
        float* __restrict__ pcv, int* __restrict__ pci) {
    const int cnt = count[0];
    const int m0  = blockIdx.x * 64;
    if (m0 >= cnt) return;
    __shared__ float Zs[32][68];      // [k][m], k-major, +4 pad
    __shared__ float Ws[32][132];     // [k][deinterleaved n], +4 pad
    __shared__ int   rowid[64];
    const int tid = threadIdx.x;
    const int cg  = tid & 15;         // 8 codes
    const int rg  = tid >> 4;         // 4 tokens
    const int y   = blockIdx.y;
    const int n0  = y * RPER;
    if (tid < 64) rowid[tid] = list[min(m0 + tid, cnt - 1)];
    __syncthreads();

    float minv[4]; int mini[4];
#pragma unroll
    for (int i = 0; i < 4; ++i) { minv[i] = 3.0e38f; mini[i] = 0x7fffffff; }

#pragma unroll 1
    for (int nt = 0; nt < RPER / 128; ++nt) {
        const int nb = n0 + nt * 128;
        float acc[4][8];
#pragma unroll
        for (int j = 0; j < 8; ++j) {
            const float wn = wnorm[nb + cg * 8 + j];
#pragma unroll
            for (int i = 0; i < 4; ++i) acc[i][j] = wn;
        }
#pragma unroll 1
        for (int k0 = 0; k0 < Kdim; k0 += 32) {
            __syncthreads();
#pragma unroll
            for (int p = 0; p < 2; ++p) {            // Z: 64 rows x 8 slots
                const int qq = p * 256 + tid;
                const int r  = qq >> 3, f = qq & 7;
                const float4 v = *(const float4*)(zt + (size_t)rowid[r] * Kdim + k0 + f * 4);
                Zs[f * 4 + 0][r] = -2.0f * v.x;
                Zs[f * 4 + 1][r] = -2.0f * v.y;
                Zs[f * 4 + 2][r] = -2.0f * v.z;
                Zs[f * 4 + 3][r] = -2.0f * v.w;
            }
#pragma unroll
            for (int p = 0; p < 4; ++p) {            // W: 128 rows x 8 slots
                const int qq = p * 256 + tid;
                const int r  = qq >> 3, f = qq & 7;
                const float4 u = *(const float4*)(w + (size_t)(nb + r) * Kdim + k0 + f * 4);
                const int pos = ((r & 4) ? 64 : 0) + (r >> 3) * 4 + (r & 3);
                Ws[f * 4 + 0][pos] = u.x;
                Ws[f * 4 + 1][pos] = u.y;
                Ws[f * 4 + 2][pos] = u.z;
                Ws[f * 4 + 3][pos] = u.w;
            }
            __syncthreads();
#pragma unroll 4
            for (int k = 0; k < 32; ++k) {
                const float4 za  = *(const float4*)&Zs[k][rg * 4];
                const float4 wb0 = *(const float4*)&Ws[k][cg * 4];
                const float4 wb1 = *(const float4*)&Ws[k][64 + cg * 4];
                const float zr[4] = {za.x, za.y, za.z, za.w};
                const float wb[8] = {wb0.x, wb0.y, wb0.z, wb0.w,
                                     wb1.x, wb1.y, wb1.z, wb1.w};
#pragma unroll
                for (int i = 0; i < 4; ++i)
#pragma unroll
                    for (int j = 0; j < 8; ++j)
                        acc[i][j] = fmaf(zr[i], wb[j], acc[i][j]);
            }
        }
#pragma unroll
        for (int i = 0; i < 4; ++i)
#pragma unroll
            for (int j = 0; j < 8; ++j) {
                const float v  = acc[i][j];
                const int idx  = nb + cg * 8 + j;
                if (v < minv[i] || (v == minv[i] && idx < mini[i])) {
                    minv[i] = v; mini[i] = idx;
                }
            }
    }
    // cross-cg reduction: 16 partials per token row
    __syncthreads();
    float* redv = (float*)&Zs[0][0];   // [64][16]
    int*   redi = (int*)&Ws[0][0];
#pragma unroll
    for (int i = 0; i < 4; ++i) {
        redv[(rg * 4 + i) * 16 + cg] = minv[i];
        redi[(rg * 4 + i) * 16 + cg] = mini[i];
    }
    __syncthreads();
    if (tid < 64) {
        float bv = 3.0e38f; int bi = 0x7fffffff;
#pragma unroll
        for (int c = 0; c < 16; ++c) {
            const float v = redv[tid * 16 + c];
            const int   x = redi[tid * 16 + c];
            if (v < bv || (v == bv && x < bi)) { bv = v; bi = x; }
        }
        pcv[(size_t)rowid[tid] * RSPLIT + y] = bv;
        pci[(size_t)rowid[tid] * RSPLIT + y] = bi;
    }
}

// ---------------------------------------------------------------------------
// Kernel 6: gather z_q = weight[idx] + float indices; flagged tokens merge
// their 32 exact rescue partials in-wave first (inf-padded butterfly).
__global__ __launch_bounds__(256) void k_gather(
        const float* __restrict__ w, const int* __restrict__ fidx,
        const int* __restrict__ flag,
        const float* __restrict__ pcv, const int* __restrict__ pci,
        float* __restrict__ zq, float* __restrict__ idx_out) {
    const int token = blockIdx.x * 4 + (threadIdx.x >> 6);
    const int lane  = threadIdx.x & 63;
    int bi = fidx[token];
    if (flag[token]) {
        float v = 3.0e38f; int ii = 0x7fffffff;
        if (lane < RSPLIT) {
            v  = pcv[(size_t)token * RSPLIT + lane];
            ii = pci[(size_t)token * RSPLIT + lane];
        }
#pragma unroll
        for (int msk = 1; msk < 64; msk <<= 1) {
            const float ov = __shfl_xor(v, msk, 64);
            const int   oi = __shfl_xor(ii, msk, 64);
            if (ov < v || (ov == v && oi < ii)) { v = ov; ii = oi; }
        }
        bi = ii;
    }
    const float4 u = *(const float4*)(w + (size_t)bi * Kdim + lane * 4);
    *(float4*)(zq + (size_t)token * Kdim + lane * 4) = u;
    if (lane == 0) idx_out[token] = (float)bi;
}

// ---------------------------------------------------------------------------
extern "C" void kernel_launch(void* const* d_in, const int* in_sizes, int n_in,
                              void* d_out, int out_size, void* d_ws, size_t ws_size,
                              hipStream_t stream) {
    const float* z = (const float*)d_in[0];
    const float* w = (const float*)d_in[1];

    float* z_out  = (float*)d_out;                          // [16384, 256]
    float* zq     = z_out + (size_t)Mtok * Kdim;            // [16384, 256]
    float* idxout = zq + (size_t)Mtok * Kdim;               // [16384]

    char* ws = (char*)d_ws;
    f16*   sh    = (f16*)ws;                       ws += (size_t)Mtok * Kdim * 2;
    f16*   whc   = (f16*)ws;                       ws += (size_t)Ncode * Kdim * 2;
    float* wnorm = (float*)ws;                     ws += (size_t)Ncode * 4;
    float* pv1   = (float*)ws;                     ws += (size_t)NSPLIT * Mtok * 4;
    int*   pi1   = (int*)ws;                       ws += (size_t)NSPLIT * Mtok * 4;
    float* pv2   = (float*)ws;                     ws += (size_t)NSPLIT * Mtok * 4;
    int*   fidx  = (int*)ws;                       ws += (size_t)Mtok * 4;
    int*   flag  = (int*)ws;                       ws += (size_t)Mtok * 4;
    int*   list  = (int*)ws;                       ws += (size_t)Mtok * 4;
    int*   count = (int*)ws;                       ws += 128;
    int*   wmax  = (int*)ws;                       ws += 128;
    float* pcv   = (float*)ws;                     ws += (size_t)Mtok * RSPLIT * 4;
    int*   pci   = (int*)ws;                       ws += (size_t)Mtok * RSPLIT * 4;

    k_prep<<<dim3(1024 / 32, Kdim / 32, 16), dim3(32, 8), 0, stream>>>(z, z_out, sh, count);
    k_wsplit<<<dim3(Ncode), dim3(64), 0, stream>>>(w, wnorm, whc, wmax);
    k_mfma<<<dim3((Mtok / 256) * NSPLIT), dim3(256), 0, stream>>>(sh, whc, wnorm,
                                                                  pv1, pi1, pv2);
    k_merge<<<dim3(Mtok / 4), dim3(256), 0, stream>>>(sh, pv1, pi1, pv2, wmax,
                                                      fidx, flag, list, count);
    k_rescue<<<dim3(Mtok / 64, RSPLIT), dim3(256), 0, stream>>>(z_out, w, wnorm,
                                                                list, count, pcv, pci);
    k_gather<<<dim3(Mtok / 4), dim3(256), 0, stream>>>(w, fidx, flag, pcv, pci,
                                                       zq, idxout);
}

// Round 9
// 444.103 us; speedup vs baseline: 1.7283x; 1.1118x over previous
//
#include <hip/hip_runtime.h>
#include <hip/hip_bf16.h>
#include <cstddef>
#include <cstdint>

typedef _Float16 f16;
typedef unsigned int u32;
typedef unsigned long long u64;

#define Mtok  16384
#define Ncode 8192
#define Kdim  256
#define NSPLIT 8
#define NPER  (Ncode / NSPLIT)    // 1024 codes per split (MFMA kernel)

typedef f16   f16x8 __attribute__((ext_vector_type(8)));
typedef f16   f16x4 __attribute__((ext_vector_type(4)));
typedef float f32x4 __attribute__((ext_vector_type(4)));

#define LDSP(p) ((__attribute__((address_space(3))) void*)(p))
#define GPTR(p) ((const __attribute__((address_space(1))) void*)(p))

__device__ __forceinline__ u32 okey(float f) {
    const u32 b = __float_as_uint(f);
    return (b & 0x80000000u) ? ~b : (b | 0x80000000u);   // monotonic float->uint
}

// ---------------------------------------------------------------------------
// Kernel 1: transpose z -> z_out (fp32) + sh = fp16(-2z) [Mtok][256].
// Zeroes the two rescue counters (stream-ordered before k_merge).
__global__ __launch_bounds__(256) void k_prep(const float* __restrict__ z,
        float* __restrict__ z_out, f16* __restrict__ sh, int* __restrict__ count) {
    __shared__ float tile[32][33];
    const int b  = blockIdx.z;
    const int c0 = blockIdx.y * 32;
    const int p0 = blockIdx.x * 32;
    const int tx = threadIdx.x;   // 0..31
    const int ty = threadIdx.y;   // 0..7
    if (b == 0 && c0 == 0 && p0 == 0 && ty == 0 && tx < 2) count[tx] = 0;
    const float* src = z + ((size_t)b * Kdim + c0) * 1024 + p0;
#pragma unroll
    for (int i = 0; i < 32; i += 8)
        tile[ty + i][tx] = src[(size_t)(ty + i) * 1024 + tx];
    __syncthreads();
#pragma unroll
    for (int i = 0; i < 32; i += 8) {
        const float v = tile[tx][ty + i];
        const size_t m = (size_t)b * 1024 + p0 + ty + i;
        const int    c = c0 + tx;
        z_out[m * Kdim + c] = v;
        sh[m * Kdim + c] = (f16)(-2.0f * v);
    }
}

// ---------------------------------------------------------------------------
// Kernel 2: wnorm[n]=||w_n||^2, whc = fp16(w) chunk-major [c=k/8][n][8],
// wmax = max bits of wnorm via signed atomicMax. One wave per row.
__global__ __launch_bounds__(64) void k_wsplit(const float* __restrict__ w,
        float* __restrict__ wnorm, f16* __restrict__ whc, int* __restrict__ wmax) {
    const int row  = blockIdx.x;
    const int lane = threadIdx.x;
    const float4 v = ((const float4*)(w + (size_t)row * Kdim))[lane];
    float s = v.x * v.x + v.y * v.y + v.z * v.z + v.w * v.w;
#pragma unroll
    for (int off = 32; off > 0; off >>= 1)
        s += __shfl_down(s, off, 64);
    if (lane == 0) {
        wnorm[row] = s;
        atomicMax(wmax, __float_as_int(s));
    }
    const int c   = lane >> 1;
    const int pos = (lane & 1) * 4;
    f16x4 p;
    p[0] = (f16)v.x; p[1] = (f16)v.y; p[2] = (f16)v.z; p[3] = (f16)v.w;
    *(f16x4*)(whc + ((size_t)c * Ncode + row) * 8 + pos) = p;
}

// ---------------------------------------------------------------------------
// Kernel 3: fp16 single-pass MFMA distance GEMM + packed per-split top-2.
__global__ __launch_bounds__(256, 2) void k_mfma(
        const f16* __restrict__ sh, const f16* __restrict__ whc,
        const float* __restrict__ wnorm,
        float* __restrict__ pv1, int* __restrict__ pi1, float* __restrict__ pv2) {
    __shared__ __align__(16) f16 Bs[32 * 256];   // [chunk][32 rows][8] = 16 KB
    const int tid  = threadIdx.x;
    const int w    = tid >> 6;
    const int lane = tid & 63;
    const int l15  = lane & 15;
    const int q    = lane >> 4;
    const int y    = blockIdx.x & 7;
    const int x    = blockIdx.x >> 3;
    const int m0   = x * 256;
    const int n0   = y * NPER;

    f16x8 a[4][8];
#pragma unroll
    for (int i = 0; i < 4; ++i)
#pragma unroll
        for (int c = 0; c < 8; ++c)
            a[i][c] = *(const f16x8*)(sh +
                (size_t)(m0 + w * 64 + i * 16 + l15) * Kdim + c * 32 + q * 8);

    u32 u1[16], u2[16];
#pragma unroll
    for (int s = 0; s < 16; ++s) { u1[s] = 0xFFFFFFFFu; u2[s] = 0xFFFFFFFFu; }

#pragma unroll 1
    for (int nt = 0; nt < NPER / 32; ++nt) {
        const int nb = n0 + nt * 32;
        __syncthreads();
#pragma unroll
        for (int ii = 0; ii < 4; ++ii) {
            const int c2 = (w * 4 + ii) * 2;
            const int ch = c2 + (lane >> 5);
            const int nr = lane & 31;
            __builtin_amdgcn_global_load_lds(
                GPTR(whc + ((size_t)ch * Ncode + nb + nr) * 8),
                LDSP(Bs + (size_t)c2 * 256), 16, 0, 0);
        }
        __syncthreads();
        f32x4 acc[4][2];
#pragma unroll
        for (int j = 0; j < 2; ++j) {
            const float wv = wnorm[nb + j * 16 + l15] + 1024.0f;
#pragma unroll
            for (int i = 0; i < 4; ++i) {
                acc[i][j][0] = wv; acc[i][j][1] = wv;
                acc[i][j][2] = wv; acc[i][j][3] = wv;
            }
        }
#pragma unroll
        for (int cc = 0; cc < 8; ++cc)
#pragma unroll
            for (int j = 0; j < 2; ++j) {
                const f16x8 b = *(const f16x8*)&Bs[(cc * 4 + q) * 256 + (j * 16 + l15) * 8];
#pragma unroll
                for (int i = 0; i < 4; ++i)
                    acc[i][j] = __builtin_amdgcn_mfma_f32_16x16x32_f16(
                        a[i][cc], b, acc[i][j], 0, 0, 0);
            }
#pragma unroll
        for (int i = 0; i < 4; ++i)
#pragma unroll
            for (int j = 0; j < 2; ++j)
#pragma unroll
                for (int r = 0; r < 4; ++r) {
                    const int s = i * 4 + r;
                    const u32 key = (__float_as_uint(acc[i][j][r]) & 0xFFFFFFC0u)
                                    | (u32)(nt * 2 + j);
                    const u32 t2 = u1[s] > key ? u1[s] : key;
                    u2[s] = u2[s] < t2 ? u2[s] : t2;
                    u1[s] = u1[s] < key ? u1[s] : key;
                }
    }
    float v1[16], v2[16]; int i1[16];
#pragma unroll
    for (int s = 0; s < 16; ++s) {
        v1[s] = __uint_as_float(u1[s] & 0xFFFFFFC0u);
        v2[s] = __uint_as_float(u2[s] & 0xFFFFFFC0u);
        const int local = (int)(u1[s] & 63u);
        i1[s] = n0 + (local >> 1) * 32 + (local & 1) * 16 + l15;
    }
#pragma unroll
    for (int msk = 1; msk < 16; msk <<= 1) {
#pragma unroll
        for (int s = 0; s < 16; ++s) {
            const float ov1 = __shfl_xor(v1[s], msk, 64);
            const int   oi1 = __shfl_xor(i1[s], msk, 64);
            const float ov2 = __shfl_xor(v2[s], msk, 64);
            const bool  keep = (v1[s] < ov1) || (v1[s] == ov1 && i1[s] < oi1);
            const float lose = keep ? ov1 : v1[s];
            v1[s] = keep ? v1[s] : ov1;
            i1[s] = keep ? i1[s] : oi1;
            v2[s] = fminf(fminf(v2[s], ov2), lose);
        }
    }
    if (l15 == 0) {
#pragma unroll
        for (int i = 0; i < 4; ++i)
#pragma unroll
            for (int r = 0; r < 4; ++r) {
                const int s = i * 4 + r;
                const int m = m0 + w * 64 + i * 16 + q * 4 + r;
                pv1[(size_t)y * Mtok + m] = v1[s];
                pi1[(size_t)y * Mtok + m] = i1[s];
                pv2[(size_t)y * Mtok + m] = v2[s];
            }
    }
}

// ---------------------------------------------------------------------------
// Kernel 4: merge 8 split partials; build EXACT-rescue work lists.
// lim = b1 + th (th >= 2*error bound, validated absmax=0 rounds 6-8).
// Candidate codes: split winners with v1 <= lim (single-dot rescore).
// Scan splits: v2[s] <= lim (two near-min codes in one split -> full
// 1024-code exact scan of that split; codes below top-2 are >= v2 > lim
// otherwise). Winner always rescored. slot init = ~0 for flagged tokens.
__global__ __launch_bounds__(256) void k_merge(
        const f16* __restrict__ sh,
        const float* __restrict__ pv1, const int* __restrict__ pi1,
        const float* __restrict__ pv2, const int* __restrict__ wmax,
        int* __restrict__ fidx, int* __restrict__ flag,
        int2* __restrict__ candList, int2* __restrict__ scanList,
        int* __restrict__ count, u64* __restrict__ slot) {
    const int t    = blockIdx.x * 4 + (threadIdx.x >> 6);
    const int lane = threadIdx.x & 63;
    const f16x4 p = *(const f16x4*)(sh + (size_t)t * Kdim + lane * 4);
    float s2 = 0.f;
#pragma unroll
    for (int i = 0; i < 4; ++i) { const float e = (float)p[i]; s2 = fmaf(e, e, s2); }
#pragma unroll
    for (int off = 32; off > 0; off >>= 1)
        s2 += __shfl_down(s2, off, 64);
    if (lane == 0) {
        float v1a[NSPLIT], v2a[NSPLIT]; int i1a[NSPLIT];
#pragma unroll
        for (int s = 0; s < NSPLIT; ++s) {
            v1a[s] = pv1[(size_t)s * Mtok + t];
            i1a[s] = pi1[(size_t)s * Mtok + t];
            v2a[s] = pv2[(size_t)s * Mtok + t];
        }
        float b1 = 3.0e38f; int bi = 0x7fffffff;
#pragma unroll
        for (int s = 0; s < NSPLIT; ++s) {
            if (v1a[s] < b1 || (v1a[s] == b1 && i1a[s] < bi)) { b1 = v1a[s]; bi = i1a[s]; }
        }
        const float Wm  = sqrtf(__int_as_float(wmax[0]));
        const float th  = 0.00205f * sqrtf(s2) * Wm + 0.12f;
        const float lim = b1 + th;
        bool extra = false;
#pragma unroll
        for (int s = 0; s < NSPLIT; ++s) {
            if (v2a[s] <= lim) extra = true;
            if (v1a[s] <= lim && i1a[s] != bi) extra = true;
        }
        fidx[t] = bi;
        flag[t] = extra ? 1 : 0;
        if (extra) {
            slot[t] = 0xFFFFFFFFFFFFFFFFull;
            int pos = atomicAdd(&count[0], 1);
            candList[pos] = make_int2(t, bi);
#pragma unroll
            for (int s = 0; s < NSPLIT; ++s) {
                if (v1a[s] <= lim && i1a[s] != bi) {
                    pos = atomicAdd(&count[0], 1);
                    candList[pos] = make_int2(t, i1a[s]);
                }
                if (v2a[s] <= lim) {
                    pos = atomicAdd(&count[1], 1);
                    scanList[pos] = make_int2(t, s);
                }
            }
        }
    }
}

// ---------------------------------------------------------------------------
// Kernel 5a: exact rescore of candidate (token, code) pairs. One wave per
// pair, coalesced 1 KB row reads, identical butterfly order to k_scan so
// duplicated (t,n) evaluations are bitwise equal. Lex-min via u64 atomicMin.
__global__ __launch_bounds__(256) void k_rescore(
        const float* __restrict__ zt, const float* __restrict__ w,
        const float* __restrict__ wnorm, const int2* __restrict__ candList,
        const int* __restrict__ count, u64* __restrict__ slot) {
    const int wid  = blockIdx.x * 4 + (threadIdx.x >> 6);
    const int lane = threadIdx.x & 63;
    const int cnt  = count[0];
    for (int i = wid; i < cnt; i += gridDim.x * 4) {
        const int2 c = candList[i];
        const float4 zv = ((const float4*)(zt + (size_t)c.x * Kdim))[lane];
        const float4 wr = ((const float4*)(w  + (size_t)c.y * Kdim))[lane];
        float s = fmaf(wr.x, zv.x, fmaf(wr.y, zv.y, fmaf(wr.z, zv.z, wr.w * zv.w)));
#pragma unroll
        for (int msk = 1; msk < 64; msk <<= 1)
            s += __shfl_xor(s, msk, 64);
        const float d = wnorm[c.y] - 2.0f * s;
        if (lane == 0)
            atomicMin(&slot[c.x], ((u64)okey(d) << 32) | (u32)c.y);
    }
}

// ---------------------------------------------------------------------------
// Kernel 5b: exact full scan of flagged (token, split) pairs. One block per
// pair; wave wv covers rows wv, wv+4, ... of the split's 1024 codes with
// coalesced whole-row reads; per-wave running u64-lex min, one atomicMin.
__global__ __launch_bounds__(256) void k_scan(
        const float* __restrict__ zt, const float* __restrict__ w,
        const float* __restrict__ wnorm, const int2* __restrict__ scanList,
        const int* __restrict__ count, u64* __restrict__ slot) {
    const int wv   = threadIdx.x >> 6;
    const int lane = threadIdx.x & 63;
    const int cnt  = count[1];
    for (int i = blockIdx.x; i < cnt; i += gridDim.x) {
        const int2 pr = scanList[i];
        const float4 zv = ((const float4*)(zt + (size_t)pr.x * Kdim))[lane];
        const int n0 = pr.y * NPER;
        u64 best = 0xFFFFFFFFFFFFFFFFull;
        for (int r = wv; r < NPER; r += 4) {
            const int n = n0 + r;
            const float4 wr = ((const float4*)(w + (size_t)n * Kdim))[lane];
            float s = fmaf(wr.x, zv.x, fmaf(wr.y, zv.y, fmaf(wr.z, zv.z, wr.w * zv.w)));
#pragma unroll
            for (int msk = 1; msk < 64; msk <<= 1)
                s += __shfl_xor(s, msk, 64);
            const float d = wnorm[n] - 2.0f * s;
            const u64 key = ((u64)okey(d) << 32) | (u32)n;
            best = best < key ? best : key;
        }
        if (lane == 0) atomicMin(&slot[pr.x], best);
    }
}

// ---------------------------------------------------------------------------
// Kernel 6: gather z_q = weight[idx] + float indices; flagged tokens take
// the exact winner from their slot (low 32 bits of the lex-min key).
__global__ __launch_bounds__(256) void k_gather(
        const float* __restrict__ w, const int* __restrict__ fidx,
        const int* __restrict__ flag, const u64* __restrict__ slot,
        float* __restrict__ zq, float* __restrict__ idx_out) {
    const int token = blockIdx.x * 4 + (threadIdx.x >> 6);
    const int lane  = threadIdx.x & 63;
    int bi = fidx[token];
    if (flag[token]) bi = (int)(u32)(slot[token] & 0xFFFFFFFFull);
    const float4 u = *(const float4*)(w + (size_t)bi * Kdim + lane * 4);
    *(float4*)(zq + (size_t)token * Kdim + lane * 4) = u;
    if (lane == 0) idx_out[token] = (float)bi;
}

// ---------------------------------------------------------------------------
extern "C" void kernel_launch(void* const* d_in, const int* in_sizes, int n_in,
                              void* d_out, int out_size, void* d_ws, size_t ws_size,
                              hipStream_t stream) {
    const float* z = (const float*)d_in[0];
    const float* w = (const float*)d_in[1];

    float* z_out  = (float*)d_out;                          // [16384, 256]
    float* zq     = z_out + (size_t)Mtok * Kdim;            // [16384, 256]
    float* idxout = zq + (size_t)Mtok * Kdim;               // [16384]

    char* ws = (char*)d_ws;
    f16*   sh    = (f16*)ws;                       ws += (size_t)Mtok * Kdim * 2;
    f16*   whc   = (f16*)ws;                       ws += (size_t)Ncode * Kdim * 2;
    float* wnorm = (float*)ws;                     ws += (size_t)Ncode * 4;
    float* pv1   = (float*)ws;                     ws += (size_t)NSPLIT * Mtok * 4;
    int*   pi1   = (int*)ws;                       ws += (size_t)NSPLIT * Mtok * 4;
    float* pv2   = (float*)ws;                     ws += (size_t)NSPLIT * Mtok * 4;
    int*   fidx  = (int*)ws;                       ws += (size_t)Mtok * 4;
    int*   flag  = (int*)ws;                       ws += (size_t)Mtok * 4;
    int2*  candL = (int2*)ws;                      ws += (size_t)Mtok * NSPLIT * 8;
    int2*  scanL = (int2*)ws;                      ws += (size_t)Mtok * NSPLIT * 8;
    int*   count = (int*)ws;                       ws += 128;
    int*   wmax  = (int*)ws;                       ws += 128;
    u64*   slot  = (u64*)ws;                       ws += (size_t)Mtok * 8;

    k_prep<<<dim3(1024 / 32, Kdim / 32, 16), dim3(32, 8), 0, stream>>>(z, z_out, sh, count);
    k_wsplit<<<dim3(Ncode), dim3(64), 0, stream>>>(w, wnorm, whc, wmax);
    k_mfma<<<dim3((Mtok / 256) * NSPLIT), dim3(256), 0, stream>>>(sh, whc, wnorm,
                                                                  pv1, pi1, pv2);
    k_merge<<<dim3(Mtok / 4), dim3(256), 0, stream>>>(sh, pv1, pi1, pv2, wmax,
                                                      fidx, flag, candL, scanL,
                                                      count, slot);
    k_rescore<<<dim3(512), dim3(256), 0, stream>>>(z_out, w, wnorm, candL, count, slot);
    k_scan<<<dim3(1024), dim3(256), 0, stream>>>(z_out, w, wnorm, scanL, count, slot);
    k_gather<<<dim3(Mtok / 4), dim3(256), 0, stream>>>(w, fidx, flag, slot,
                                                       zq, idxout);
}